// Round 15
// baseline (360.153 us; speedup 1.0000x reference)
//
#include <hip/hip_runtime.h>
#include <hip/hip_fp16.h>

typedef _Float16 f16;
typedef _Float16 f16x8 __attribute__((ext_vector_type(8)));
typedef _Float16 f16x4 __attribute__((ext_vector_type(4)));
typedef float f32x4 __attribute__((ext_vector_type(4)));

#define QQ 36864

// feat (B,C,H,W) f32 -> featT (B,H,W,C) f16
__global__ void transpose_feat_k(const float* __restrict__ feat, f16* __restrict__ featT) {
    int idx = blockIdx.x * 256 + threadIdx.x;   // over B*H*W*C, c fastest
    int c = idx & 63;
    int rest = idx >> 6;
    int x = rest & 63;
    int y = (rest >> 6) & 63;
    int b = rest >> 12;
    featT[idx] = (f16)feat[((b*64 + c)*64 + y)*64 + x];
}

// Pack W (kreal x ncols f32, row-major) + optional bias row into fragment
// order, kslot(g,i) = 8g + i.
// dst[((ks*nnt + nt)*64 + lane)*8 + i] = W[refrow(ks*32+8*(lane>>4)+i)][nt*16+(lane&15)]
// k == kreal -> bias row (only reachable if nks*32 > kreal).
// perm: unfold reorder for layer 0 (our k' = k9*64 + c -> ref k = c*9 + k9, k<576).
__global__ void pack_w_k2(const float* __restrict__ w, const float* __restrict__ bias,
                          f16* __restrict__ dst, int nks, int nnt, int kreal,
                          int ncols, int perm) {
    int e = blockIdx.x * 256 + threadIdx.x;
    if (e >= nks * nnt * 512) return;
    int i    = e & 7;
    int lane = (e >> 3) & 63;
    int nt   = (e >> 9) % nnt;
    int ks   = (e >> 9) / nnt;
    int n = nt*16 + (lane & 15);
    int k = ks*32 + (lane >> 4)*8 + i;
    float v = 0.f;
    if (n < ncols) {
        if (k < kreal) {
            int rk = k;
            if (perm && k < 576) rk = (k & 63)*9 + (k >> 6);
            v = w[rk*ncols + n];
        } else if (k == kreal) {
            v = bias[n];
        }
    }
    dst[e] = (f16)v;
}

// Per-pixel layer-0 main GEMM: P[pix][n] = sum_{k<576} X[pix][k'] * W0[k'][n]
// (NO bias, NO tail -- those are applied per-query in the main kernel).
// One block = one image row (b,y), 64 pixels x 256 n.
__global__ __launch_bounds__(256, 2)
void conv0_k(const f16* __restrict__ featT, const f16* __restrict__ pw0,
             float* __restrict__ P)
{
    __shared__ __align__(16) f16 Xs[2][64*64];

    const int t   = threadIdx.x;           // 256 threads, 4 waves
    const int blk = blockIdx.x;            // 256 blocks
    const int by  = blk >> 6;              // batch
    const int y   = blk & 63;              // image row
    const int lane = t & 63;
    const int wv = t >> 6;
    const int l15 = lane & 15, g = lane >> 4;

    auto stage_ld = [&](int kc, int item) -> f16x8 {
        const int it = t + item*256;
        const int sr = it >> 3, sc = it & 7;   // sr = pixel x, sc = 8-ch chunk
        const int kh = kc / 3, kw = kc - kh*3;
        const int yy = y + kh - 1;
        const int xx = sr + kw - 1;
        f16x8 v = {0,0,0,0,0,0,0,0};
        if (yy >= 0 && yy < 64 && xx >= 0 && xx < 64)
            v = *(const f16x8*)&featT[(((by*64 + yy)*64 + xx) << 6) + sc*8];
        return v;
    };
    auto stage_st = [&](int bufi, f16x8 v, int item) {
        const int it = t + item*256;
        const int sr = it >> 3, sc = it & 7;
        *(f16x8*)&Xs[bufi][sr*64 + ((sc ^ (sr & 7)) << 3)] = v;
    };
    auto ldXs = [&](int bufi, int j, int m) -> f16x8 {
        return *(const f16x8*)&Xs[bufi][m*64 + ((((j << 2) + g) ^ (m & 7)) << 3)];
    };
    auto ldB = [&](int ks, int nf) -> f16x8 {
        return *(const f16x8*)&pw0[((ks*16 + wv*4 + nf)*64 + lane)*8];
    };

    f32x4 acc[4][4];
    #pragma unroll
    for (int mf = 0; mf < 4; ++mf)
        #pragma unroll
        for (int nf = 0; nf < 4; ++nf)
            acc[mf][nf] = (f32x4){0.f, 0.f, 0.f, 0.f};

    f16x8 bc[4], bn[4];
    f16x8 s0a, s0b, s1a, s1b;
    s0a = stage_ld(0, 0); s0b = stage_ld(0, 1);
    #pragma unroll
    for (int nf = 0; nf < 4; ++nf) bc[nf] = ldB(0, nf);
    stage_st(0, s0a, 0); stage_st(0, s0b, 1);
    s1a = stage_ld(1, 0); s1b = stage_ld(1, 1);
    __syncthreads();

    #pragma unroll
    for (int kc = 0; kc < 9; ++kc) {
        #pragma unroll
        for (int j = 0; j < 2; ++j) {
            const int ks = kc*2 + j;               // 0..17
            #pragma unroll
            for (int nf = 0; nf < 4; ++nf) bn[nf] = ldB(ks + 1, nf); // ks+1<=18, dead at 18
            #pragma unroll
            for (int mf = 0; mf < 4; ++mf) {
                f16x8 a = ldXs(kc & 1, j, mf*16 + l15);
                #pragma unroll
                for (int nf = 0; nf < 4; ++nf)
                    acc[mf][nf] = __builtin_amdgcn_mfma_f32_16x16x32_f16(bc[nf], a, acc[mf][nf], 0, 0, 0);
            }
            #pragma unroll
            for (int nf = 0; nf < 4; ++nf) bc[nf] = bn[nf];
        }
        if (kc < 8) {
            if (kc & 1) { stage_st((kc + 1) & 1, s0a, 0); stage_st((kc + 1) & 1, s0b, 1); }
            else        { stage_st((kc + 1) & 1, s1a, 0); stage_st((kc + 1) & 1, s1b, 1); }
            if (kc < 7) {
                if (kc & 1) { s1a = stage_ld(kc + 2, 0); s1b = stage_ld(kc + 2, 1); }
                else        { s0a = stage_ld(kc + 2, 0); s0b = stage_ld(kc + 2, 1); }
            }
            __syncthreads();
        }
    }

    // D' layout: lane l15 = pixel row m, regs = 4 consecutive n.
    #pragma unroll
    for (int mf = 0; mf < 4; ++mf) {
        float* prow = &P[(blk*64 + mf*16 + l15)*256];
        #pragma unroll
        for (int nf = 0; nf < 4; ++nf)
            *(f32x4*)&prow[wv*64 + nf*16 + 4*g] = acc[mf][nf];
    }
}

__global__ __launch_bounds__(512, 4)
void liif_main_k(const float* __restrict__ P,
                 const f16* __restrict__ pw0, const f16* __restrict__ pw1,
                 const f16* __restrict__ pw2, const f16* __restrict__ pw3,
                 const f16* __restrict__ pw4,
                 const float* __restrict__ bias1, const float* __restrict__ bias2,
                 const float* __restrict__ bias3, const float* __restrict__ bias4,
                 const float* __restrict__ coord, const float* __restrict__ cell,
                 float* __restrict__ out)
{
    // Hs: PING-PONG pair of 64 rows x 256 halves, row = 512B = 32 chunks of 16B.
    // Physical chunk index = logical chunk ^ (row & 7)  -> conflict-free b128.
    __shared__ __align__(16) f16 Hs[2][64*256];
    __shared__ int   pixs[64];
    __shared__ __align__(8) f16 tailA[64][4];
    __shared__ float areas[64];

    const int t   = threadIdx.x;           // 512 threads, 8 waves
    const int blk = blockIdx.x;            // 9216 blocks x 64 rows
    const int row0 = blk * 64;             // global row base (row = 4*q + s)
    const int bb  = blk / 2304;            // batch index

    // ---------------- phase 0: per-row meta ----------------
    if (t < 64) {
        const int r = t;
        const int grow = row0 + r;
        const int q = grow >> 2;           // global query index (b*QQ + ql)
        const int s = grow & 3;
        const float c0  = coord[q*2 + 0];
        const float c1  = coord[q*2 + 1];
        const float ce0 = cell[q*2 + 0] * 64.f;
        const float ce1 = cell[q*2 + 1] * 64.f;
        const float vx = (s & 2) ? 1.f : -1.f;
        const float vy = (s & 1) ? 1.f : -1.f;
        float cx = c0 + vx*(1.f/64.f) + 1e-6f;
        cx = fminf(fmaxf(cx, -1.f + 1e-6f), 1.f - 1e-6f);
        float cy = c1 + vy*(1.f/64.f) + 1e-6f;
        cy = fminf(fmaxf(cy, -1.f + 1e-6f), 1.f - 1e-6f);
        float fiy = floorf(((cx + 1.f)*64.f - 1.f)*0.5f + 0.5f);
        fiy = fminf(fmaxf(fiy, 0.f), 63.f);
        float fix = floorf(((cy + 1.f)*64.f - 1.f)*0.5f + 0.5f);
        fix = fminf(fmaxf(fix, 0.f), 63.f);
        const float qcx = (fiy + 0.5f)*(2.f/64.f) - 1.f;
        const float qcy = (fix + 0.5f)*(2.f/64.f) - 1.f;
        const float rx = (c0 - qcx)*64.f;
        const float ry = (c1 - qcy)*64.f;
        pixs[r] = bb*4096 + (int)fiy*64 + (int)fix;
        tailA[r][0] = (f16)rx;  tailA[r][1] = (f16)ry;
        tailA[r][2] = (f16)ce0; tailA[r][3] = (f16)ce1;
        areas[r] = fabsf(rx*ry) + 1e-9f;
    }
    __syncthreads();

    const int lane = t & 63;
    const int wv = t >> 6;                 // wave 0..7
    const int wm = wv >> 2, wn = wv & 3;   // 2m x 4n wave grid
    const int m0 = wm * 32;
    const int l15 = lane & 15, g = lane >> 4;

    auto ldHs = [&](const f16* hs, int ks, int m) -> f16x8 {
        return *(const f16x8*)&hs[m*256 + (((ks*4 + g) ^ (m & 7)) << 3)];
    };
    auto ldB = [&](const f16* __restrict__ pw, int ks, int nf) -> f16x8 {
        return *(const f16x8*)&pw[((ks*16 + wn*4 + nf)*64 + lane)*8];
    };

    f32x4 acc[2][4];
    f16x8 bc[4], bn[4];

    // ---------------- layer 0: acc = P[pix] ; + tail/bias k-slot ----------------
    #pragma unroll
    for (int nf = 0; nf < 4; ++nf) bc[nf] = ldB(pw0, 18, nf);
    #pragma unroll
    for (int mf = 0; mf < 2; ++mf) {
        const float* prow = &P[pixs[m0 + mf*16 + l15]*256];
        #pragma unroll
        for (int nf = 0; nf < 4; ++nf)
            acc[mf][nf] = *(const f32x4*)&prow[wn*64 + nf*16 + 4*g];
    }
    // tail slot ks=18: k 576..579 = (rel_x, rel_y, cellx, celly), k 580 = bias(1.0)
    #pragma unroll
    for (int mf = 0; mf < 2; ++mf) {
        f16x8 a = (f16x8){0,0,0,0,0,0,0,0};
        if (g == 0) {
            f16x4 tv = *(const f16x4*)&tailA[m0 + mf*16 + l15][0];
            a[0] = tv[0]; a[1] = tv[1]; a[2] = tv[2]; a[3] = tv[3];
            a[4] = (f16)1.f;
        }
        #pragma unroll
        for (int nf = 0; nf < 4; ++nf)
            acc[mf][nf] = __builtin_amdgcn_mfma_f32_16x16x32_f16(bc[nf], a, acc[mf][nf], 0, 0, 0);
    }
    // preload layer-1 W[0] before the writeback
    #pragma unroll
    for (int nf = 0; nf < 4; ++nf) bc[nf] = ldB(pw1, 0, nf);

    // relu + bias + cvt + one contiguous 8B store per (mf,nf) per lane.
    // D' layout: lane l15 = m, regs = 4 consecutive n (nbase = wn*64+nf*16+4g).
    auto writeback = [&](f16* hd, const float* __restrict__ bias) {
        #pragma unroll
        for (int nf = 0; nf < 4; ++nf) {
            const int nbase = wn*64 + nf*16 + 4*g;
            float bv0 = 0.f, bv1 = 0.f, bv2 = 0.f, bv3 = 0.f;
            if (bias) {
                bv0 = bias[nbase];     bv1 = bias[nbase + 1];
                bv2 = bias[nbase + 2]; bv3 = bias[nbase + 3];
            }
            #pragma unroll
            for (int mf = 0; mf < 2; ++mf) {
                const int m = m0 + mf*16 + l15;
                f16x4 pk;
                pk[0] = (f16)fmaxf(acc[mf][nf][0] + bv0, 0.f);
                pk[1] = (f16)fmaxf(acc[mf][nf][1] + bv1, 0.f);
                pk[2] = (f16)fmaxf(acc[mf][nf][2] + bv2, 0.f);
                pk[3] = (f16)fmaxf(acc[mf][nf][3] + bv3, 0.f);
                *(f16x4*)&hd[m*256 + (((nbase >> 3) ^ (m & 7)) << 3) + (nbase & 7)] = pk;
            }
        }
    };

    writeback(Hs[0], nullptr);   // layer-0 bias was the k=580 slot
    __syncthreads();

    // ---------------- layers 1..3: K = 256 in 8 k-slots, bias via VALU ----------------
    // Ping-pong: read Hs[src], write Hs[src^1] -> single barrier per layer.
    auto mlp_layer = [&](const f16* __restrict__ pw, const f16* __restrict__ pwn,
                         const float* __restrict__ bias, int src) {
        #pragma unroll
        for (int mf = 0; mf < 2; ++mf)
            #pragma unroll
            for (int nf = 0; nf < 4; ++nf)
                acc[mf][nf] = (f32x4){0.f, 0.f, 0.f, 0.f};
        #pragma unroll
        for (int ks = 0; ks < 8; ++ks) {
            #pragma unroll
            for (int nf = 0; nf < 4; ++nf)
                bn[nf] = (ks < 7) ? ldB(pw, ks + 1, nf) : ldB(pwn, 0, nf);
            f16x8 a0 = ldHs(Hs[src], ks, m0 + l15);
            f16x8 a1 = ldHs(Hs[src], ks, m0 + 16 + l15);
            #pragma unroll
            for (int nf = 0; nf < 4; ++nf) {
                acc[0][nf] = __builtin_amdgcn_mfma_f32_16x16x32_f16(bc[nf], a0, acc[0][nf], 0, 0, 0);
                acc[1][nf] = __builtin_amdgcn_mfma_f32_16x16x32_f16(bc[nf], a1, acc[1][nf], 0, 0, 0);
            }
            #pragma unroll
            for (int nf = 0; nf < 4; ++nf) bc[nf] = bn[nf];
        }
        writeback(Hs[src ^ 1], bias);     // other buffer: no read-drain barrier
        __syncthreads();                  // writes visible before next layer reads
    };
    mlp_layer(pw1, pw2, bias1, 0);        // Hs0 -> Hs1
    mlp_layer(pw2, pw3, bias2, 1);        // Hs1 -> Hs0
    mlp_layer(pw3, pw3, bias3, 0);        // Hs0 -> Hs1   (final prefetch discarded)

    // ---------------- layer 4 (256 -> 3, MFMA, original operand order) ----------------
    if (wv < 4) {
        const int m4 = wv * 16;
        f32x4 a4 = (f32x4){0.f, 0.f, 0.f, 0.f};
        #pragma unroll
        for (int ks = 0; ks < 8; ++ks) {
            f16x8 af = ldHs(Hs[1], ks, m4 + l15);
            f16x8 bf = *(const f16x8*)&pw4[(ks*64 + lane)*8];
            a4 = __builtin_amdgcn_mfma_f32_16x16x32_f16(af, bf, a4, 0, 0, 0);
        }
        // D: lane(g,l15): rows m4+4g+r4 (the 4 shifts of a query), col l15 = out ch
        if (l15 < 3) {
            const int base = m4 + 4*g;     // local row of shift s=0
            const float a0 = areas[base], a1 = areas[base+1];
            const float a2 = areas[base+2], a3 = areas[base+3];
            const float tot = a0 + a1 + a2 + a3;
            // local_ensemble swap: pred[s] weighted by area[s^3]; weights sum to 1
            // so the b4 bias distributes out of the blend.
            const float val = (a4[0]*a3 + a4[1]*a2 + a4[2]*a1 + a4[3]*a0) / tot
                              + bias4[l15];
            out[((row0 >> 2) + wv*4 + g)*3 + l15] = val;
        }
    }
}

extern "C" void kernel_launch(void* const* d_in, const int* in_sizes, int n_in,
                              void* d_out, int out_size, void* d_ws, size_t ws_size,
                              hipStream_t stream) {
    const float* feat  = (const float*)d_in[0];
    const float* coord = (const float*)d_in[1];
    const float* cell  = (const float*)d_in[2];
    const float* w0 = (const float*)d_in[3];
    const float* b0 = (const float*)d_in[4];
    const float* w1 = (const float*)d_in[5];
    const float* b1 = (const float*)d_in[6];
    const float* w2 = (const float*)d_in[7];
    const float* b2 = (const float*)d_in[8];
    const float* w3 = (const float*)d_in[9];
    const float* b3 = (const float*)d_in[10];
    const float* w4 = (const float*)d_in[11];
    const float* b4 = (const float*)d_in[12];
    float* out = (float*)d_out;

    f16* featT = (f16*)d_ws;                 // 4*64*64*64 halves = 2 MB
    f16* pw0 = featT + 4*64*64*64;           // 19*16*512 halves (incl. tail+bias)
    f16* pw1 = pw0 + 19*16*512;              // 8*16*512 each (no bias row)
    f16* pw2 = pw1 + 8*16*512;
    f16* pw3 = pw2 + 8*16*512;
    f16* pw4 = pw3 + 8*16*512;               // 8*1*512
    float* P = (float*)(pw4 + 8*512);        // 16384 x 256 f32 = 16 MB

    transpose_feat_k<<<4096, 256, 0, stream>>>(feat, featT);
    pack_w_k2<<<608, 256, 0, stream>>>(w0, b0, pw0, 19, 16, 580, 256, 1);
    pack_w_k2<<<256, 256, 0, stream>>>(w1, b1, pw1,  8, 16, 256, 256, 0);
    pack_w_k2<<<256, 256, 0, stream>>>(w2, b2, pw2,  8, 16, 256, 256, 0);
    pack_w_k2<<<256, 256, 0, stream>>>(w3, b3, pw3,  8, 16, 256, 256, 0);
    pack_w_k2<<< 16, 256, 0, stream>>>(w4, b4, pw4,  8,  1, 256,   3, 0);
    conv0_k<<<256, 256, 0, stream>>>(featT, pw0, P);
    liif_main_k<<<9216, 512, 0, stream>>>(P, pw0, pw1, pw2, pw3, pw4,
                                          b1, b2, b3, b4,
                                          coord, cell, out);
}

// Round 16
// 288.417 us; speedup vs baseline: 1.2487x; 1.2487x over previous
//
#include <hip/hip_runtime.h>
#include <hip/hip_fp16.h>

typedef _Float16 f16;
typedef _Float16 f16x8 __attribute__((ext_vector_type(8)));
typedef _Float16 f16x4 __attribute__((ext_vector_type(4)));
typedef float f32x4 __attribute__((ext_vector_type(4)));

#define QQ 36864

// feat (B,C,H,W) f32 -> featT (B,H,W,C) f16
__global__ void transpose_feat_k(const float* __restrict__ feat, f16* __restrict__ featT) {
    int idx = blockIdx.x * 256 + threadIdx.x;   // over B*H*W*C, c fastest
    int c = idx & 63;
    int rest = idx >> 6;
    int x = rest & 63;
    int y = (rest >> 6) & 63;
    int b = rest >> 12;
    featT[idx] = (f16)feat[((b*64 + c)*64 + y)*64 + x];
}

// Pack W (kreal x ncols f32, row-major) + optional bias row into fragment
// order, kslot(g,i) = 8g + i.
// dst[((ks*nnt + nt)*64 + lane)*8 + i] = W[refrow(ks*32+8*(lane>>4)+i)][nt*16+(lane&15)]
// k == kreal -> bias row (only reachable if nks*32 > kreal).
// perm: unfold reorder for layer 0 (our k' = k9*64 + c -> ref k = c*9 + k9, k<576).
__global__ void pack_w_k2(const float* __restrict__ w, const float* __restrict__ bias,
                          f16* __restrict__ dst, int nks, int nnt, int kreal,
                          int ncols, int perm) {
    int e = blockIdx.x * 256 + threadIdx.x;
    if (e >= nks * nnt * 512) return;
    int i    = e & 7;
    int lane = (e >> 3) & 63;
    int nt   = (e >> 9) % nnt;
    int ks   = (e >> 9) / nnt;
    int n = nt*16 + (lane & 15);
    int k = ks*32 + (lane >> 4)*8 + i;
    float v = 0.f;
    if (n < ncols) {
        if (k < kreal) {
            int rk = k;
            if (perm && k < 576) rk = (k & 63)*9 + (k >> 6);
            v = w[rk*ncols + n];
        } else if (k == kreal) {
            v = bias[n];
        }
    }
    dst[e] = (f16)v;
}

// Per-pixel layer-0 main GEMM: P[pix][n] = sum_{k<576} X[pix][k'] * W0[k'][n]
// (NO bias, NO tail -- those are applied per-query in the main kernel).
// One block = one image row (b,y), 64 pixels x 256 n.
__global__ __launch_bounds__(256, 2)
void conv0_k(const f16* __restrict__ featT, const f16* __restrict__ pw0,
             float* __restrict__ P)
{
    __shared__ __align__(16) f16 Xs[2][64*64];

    const int t   = threadIdx.x;           // 256 threads, 4 waves
    const int blk = blockIdx.x;            // 256 blocks
    const int by  = blk >> 6;              // batch
    const int y   = blk & 63;              // image row
    const int lane = t & 63;
    const int wv = t >> 6;
    const int l15 = lane & 15, g = lane >> 4;

    auto stage_ld = [&](int kc, int item) -> f16x8 {
        const int it = t + item*256;
        const int sr = it >> 3, sc = it & 7;   // sr = pixel x, sc = 8-ch chunk
        const int kh = kc / 3, kw = kc - kh*3;
        const int yy = y + kh - 1;
        const int xx = sr + kw - 1;
        f16x8 v = {0,0,0,0,0,0,0,0};
        if (yy >= 0 && yy < 64 && xx >= 0 && xx < 64)
            v = *(const f16x8*)&featT[(((by*64 + yy)*64 + xx) << 6) + sc*8];
        return v;
    };
    auto stage_st = [&](int bufi, f16x8 v, int item) {
        const int it = t + item*256;
        const int sr = it >> 3, sc = it & 7;
        *(f16x8*)&Xs[bufi][sr*64 + ((sc ^ (sr & 7)) << 3)] = v;
    };
    auto ldXs = [&](int bufi, int j, int m) -> f16x8 {
        return *(const f16x8*)&Xs[bufi][m*64 + ((((j << 2) + g) ^ (m & 7)) << 3)];
    };
    auto ldB = [&](int ks, int nf) -> f16x8 {
        return *(const f16x8*)&pw0[((ks*16 + wv*4 + nf)*64 + lane)*8];
    };

    f32x4 acc[4][4];
    #pragma unroll
    for (int mf = 0; mf < 4; ++mf)
        #pragma unroll
        for (int nf = 0; nf < 4; ++nf)
            acc[mf][nf] = (f32x4){0.f, 0.f, 0.f, 0.f};

    f16x8 bc[4], bn[4];
    f16x8 s0a, s0b, s1a, s1b;
    s0a = stage_ld(0, 0); s0b = stage_ld(0, 1);
    #pragma unroll
    for (int nf = 0; nf < 4; ++nf) bc[nf] = ldB(0, nf);
    stage_st(0, s0a, 0); stage_st(0, s0b, 1);
    s1a = stage_ld(1, 0); s1b = stage_ld(1, 1);
    __syncthreads();

    #pragma unroll
    for (int kc = 0; kc < 9; ++kc) {
        #pragma unroll
        for (int j = 0; j < 2; ++j) {
            const int ks = kc*2 + j;               // 0..17
            #pragma unroll
            for (int nf = 0; nf < 4; ++nf) bn[nf] = ldB(ks + 1, nf); // ks+1<=18, dead at 18
            #pragma unroll
            for (int mf = 0; mf < 4; ++mf) {
                f16x8 a = ldXs(kc & 1, j, mf*16 + l15);
                #pragma unroll
                for (int nf = 0; nf < 4; ++nf)
                    acc[mf][nf] = __builtin_amdgcn_mfma_f32_16x16x32_f16(bc[nf], a, acc[mf][nf], 0, 0, 0);
            }
            #pragma unroll
            for (int nf = 0; nf < 4; ++nf) bc[nf] = bn[nf];
        }
        if (kc < 8) {
            if (kc & 1) { stage_st((kc + 1) & 1, s0a, 0); stage_st((kc + 1) & 1, s0b, 1); }
            else        { stage_st((kc + 1) & 1, s1a, 0); stage_st((kc + 1) & 1, s1b, 1); }
            if (kc < 7) {
                if (kc & 1) { s1a = stage_ld(kc + 2, 0); s1b = stage_ld(kc + 2, 1); }
                else        { s0a = stage_ld(kc + 2, 0); s0b = stage_ld(kc + 2, 1); }
            }
            __syncthreads();
        }
    }

    // D' layout: lane l15 = pixel row m, regs = 4 consecutive n.
    #pragma unroll
    for (int mf = 0; mf < 4; ++mf) {
        float* prow = &P[(blk*64 + mf*16 + l15)*256];
        #pragma unroll
        for (int nf = 0; nf < 4; ++nf)
            *(f32x4*)&prow[wv*64 + nf*16 + 4*g] = acc[mf][nf];
    }
}

// Main kernel: 512 threads, 8 waves in a 1m x 8n grid.
// Each wave: all 64 rows x 32 cols (2 nt)  ->  acc[4][2] = 32 regs,
// no B duplication across waves, <=128 regs -> 4 waves/SIMD.
__global__ __launch_bounds__(512, 4)
void liif_main_k(const float* __restrict__ P,
                 const f16* __restrict__ pw0, const f16* __restrict__ pw1,
                 const f16* __restrict__ pw2, const f16* __restrict__ pw3,
                 const f16* __restrict__ pw4,
                 const float* __restrict__ bias1, const float* __restrict__ bias2,
                 const float* __restrict__ bias3, const float* __restrict__ bias4,
                 const float* __restrict__ coord, const float* __restrict__ cell,
                 float* __restrict__ out)
{
    // Hs: PING-PONG pair of 64 rows x 256 halves, row = 512B = 32 chunks of 16B.
    // Physical chunk index = logical chunk ^ (row & 7)  -> conflict-free b128.
    __shared__ __align__(16) f16 Hs[2][64*256];
    __shared__ int   pixs[64];
    __shared__ __align__(8) f16 tailA[64][4];
    __shared__ float areas[64];

    const int t   = threadIdx.x;           // 512 threads, 8 waves
    const int blk = blockIdx.x;            // 9216 blocks x 64 rows
    const int row0 = blk * 64;             // global row base (row = 4*q + s)
    const int bb  = blk / 2304;            // batch index

    // ---------------- phase 0: per-row meta ----------------
    if (t < 64) {
        const int r = t;
        const int grow = row0 + r;
        const int q = grow >> 2;           // global query index (b*QQ + ql)
        const int s = grow & 3;
        const float c0  = coord[q*2 + 0];
        const float c1  = coord[q*2 + 1];
        const float ce0 = cell[q*2 + 0] * 64.f;
        const float ce1 = cell[q*2 + 1] * 64.f;
        const float vx = (s & 2) ? 1.f : -1.f;
        const float vy = (s & 1) ? 1.f : -1.f;
        float cx = c0 + vx*(1.f/64.f) + 1e-6f;
        cx = fminf(fmaxf(cx, -1.f + 1e-6f), 1.f - 1e-6f);
        float cy = c1 + vy*(1.f/64.f) + 1e-6f;
        cy = fminf(fmaxf(cy, -1.f + 1e-6f), 1.f - 1e-6f);
        float fiy = floorf(((cx + 1.f)*64.f - 1.f)*0.5f + 0.5f);
        fiy = fminf(fmaxf(fiy, 0.f), 63.f);
        float fix = floorf(((cy + 1.f)*64.f - 1.f)*0.5f + 0.5f);
        fix = fminf(fmaxf(fix, 0.f), 63.f);
        const float qcx = (fiy + 0.5f)*(2.f/64.f) - 1.f;
        const float qcy = (fix + 0.5f)*(2.f/64.f) - 1.f;
        const float rx = (c0 - qcx)*64.f;
        const float ry = (c1 - qcy)*64.f;
        pixs[r] = bb*4096 + (int)fiy*64 + (int)fix;
        tailA[r][0] = (f16)rx;  tailA[r][1] = (f16)ry;
        tailA[r][2] = (f16)ce0; tailA[r][3] = (f16)ce1;
        areas[r] = fabsf(rx*ry) + 1e-9f;
    }
    __syncthreads();

    const int lane = t & 63;
    const int wv = t >> 6;                 // wave 0..7; n-tile = wv*32
    const int l15 = lane & 15, g = lane >> 4;

    auto ldHs = [&](const f16* hs, int ks, int m) -> f16x8 {
        return *(const f16x8*)&hs[m*256 + (((ks*4 + g) ^ (m & 7)) << 3)];
    };
    // nt = wv*2 + nf, nf in {0,1}: all 16 nt covered once across 8 waves.
    auto ldB = [&](const f16* __restrict__ pw, int ks, int nf) -> f16x8 {
        return *(const f16x8*)&pw[((ks*16 + wv*2 + nf)*64 + lane)*8];
    };

    f32x4 acc[4][2];
    f16x8 bc[2], bn[2];

    // ---------------- layer 0: acc = P[pix] ; + tail/bias k-slot ----------------
    #pragma unroll
    for (int nf = 0; nf < 2; ++nf) bc[nf] = ldB(pw0, 18, nf);
    #pragma unroll
    for (int mf = 0; mf < 4; ++mf) {
        const float* prow = &P[pixs[mf*16 + l15]*256];
        #pragma unroll
        for (int nf = 0; nf < 2; ++nf)
            acc[mf][nf] = *(const f32x4*)&prow[wv*32 + nf*16 + 4*g];
    }
    // tail slot ks=18: k 576..579 = (rel_x, rel_y, cellx, celly), k 580 = bias(1.0)
    #pragma unroll
    for (int mf = 0; mf < 4; ++mf) {
        f16x8 a = (f16x8){0,0,0,0,0,0,0,0};
        if (g == 0) {
            f16x4 tv = *(const f16x4*)&tailA[mf*16 + l15][0];
            a[0] = tv[0]; a[1] = tv[1]; a[2] = tv[2]; a[3] = tv[3];
            a[4] = (f16)1.f;
        }
        #pragma unroll
        for (int nf = 0; nf < 2; ++nf)
            acc[mf][nf] = __builtin_amdgcn_mfma_f32_16x16x32_f16(bc[nf], a, acc[mf][nf], 0, 0, 0);
    }
    // preload layer-1 W[0] before the writeback
    #pragma unroll
    for (int nf = 0; nf < 2; ++nf) bc[nf] = ldB(pw1, 0, nf);

    // relu + bias + cvt + one contiguous 8B store per (mf,nf) per lane.
    // D' layout: lane l15 = m, regs = 4 consecutive n (nbase = wv*32+nf*16+4g).
    auto writeback = [&](f16* hd, const float* __restrict__ bias) {
        #pragma unroll
        for (int nf = 0; nf < 2; ++nf) {
            const int nbase = wv*32 + nf*16 + 4*g;
            float bv0 = 0.f, bv1 = 0.f, bv2 = 0.f, bv3 = 0.f;
            if (bias) {
                bv0 = bias[nbase];     bv1 = bias[nbase + 1];
                bv2 = bias[nbase + 2]; bv3 = bias[nbase + 3];
            }
            #pragma unroll
            for (int mf = 0; mf < 4; ++mf) {
                const int m = mf*16 + l15;
                f16x4 pk;
                pk[0] = (f16)fmaxf(acc[mf][nf][0] + bv0, 0.f);
                pk[1] = (f16)fmaxf(acc[mf][nf][1] + bv1, 0.f);
                pk[2] = (f16)fmaxf(acc[mf][nf][2] + bv2, 0.f);
                pk[3] = (f16)fmaxf(acc[mf][nf][3] + bv3, 0.f);
                *(f16x4*)&hd[m*256 + (((nbase >> 3) ^ (m & 7)) << 3) + (nbase & 7)] = pk;
            }
        }
    };

    writeback(Hs[0], nullptr);   // layer-0 bias was the k=580 slot
    __syncthreads();

    // ---------------- layers 1..3: K = 256 in 8 k-slots, bias via VALU ----------------
    // Ping-pong: read Hs[src], write Hs[src^1] -> single barrier per layer.
    auto mlp_layer = [&](const f16* __restrict__ pw, const f16* __restrict__ pwn,
                         const float* __restrict__ bias, int src) {
        #pragma unroll
        for (int mf = 0; mf < 4; ++mf)
            #pragma unroll
            for (int nf = 0; nf < 2; ++nf)
                acc[mf][nf] = (f32x4){0.f, 0.f, 0.f, 0.f};
        #pragma unroll
        for (int ks = 0; ks < 8; ++ks) {
            #pragma unroll
            for (int nf = 0; nf < 2; ++nf)
                bn[nf] = (ks < 7) ? ldB(pw, ks + 1, nf) : ldB(pwn, 0, nf);
            #pragma unroll
            for (int mf = 0; mf < 4; ++mf) {
                f16x8 a = ldHs(Hs[src], ks, mf*16 + l15);
                #pragma unroll
                for (int nf = 0; nf < 2; ++nf)
                    acc[mf][nf] = __builtin_amdgcn_mfma_f32_16x16x32_f16(bc[nf], a, acc[mf][nf], 0, 0, 0);
            }
            #pragma unroll
            for (int nf = 0; nf < 2; ++nf) bc[nf] = bn[nf];
        }
        writeback(Hs[src ^ 1], bias);     // other buffer: no read-drain barrier
        __syncthreads();                  // writes visible before next layer reads
    };
    mlp_layer(pw1, pw2, bias1, 0);        // Hs0 -> Hs1
    mlp_layer(pw2, pw3, bias2, 1);        // Hs1 -> Hs0
    mlp_layer(pw3, pw3, bias3, 0);        // Hs0 -> Hs1   (final prefetch discarded)

    // ---------------- layer 4 (256 -> 3, MFMA, original operand order) ----------------
    if (wv < 4) {
        const int m4 = wv * 16;
        f32x4 a4 = (f32x4){0.f, 0.f, 0.f, 0.f};
        #pragma unroll
        for (int ks = 0; ks < 8; ++ks) {
            f16x8 af = ldHs(Hs[1], ks, m4 + l15);
            f16x8 bf = *(const f16x8*)&pw4[(ks*64 + lane)*8];
            a4 = __builtin_amdgcn_mfma_f32_16x16x32_f16(af, bf, a4, 0, 0, 0);
        }
        // D: lane(g,l15): rows m4+4g+r4 (the 4 shifts of a query), col l15 = out ch
        if (l15 < 3) {
            const int base = m4 + 4*g;     // local row of shift s=0
            const float a0 = areas[base], a1 = areas[base+1];
            const float a2 = areas[base+2], a3 = areas[base+3];
            const float tot = a0 + a1 + a2 + a3;
            // local_ensemble swap: pred[s] weighted by area[s^3]; weights sum to 1
            // so the b4 bias distributes out of the blend.
            const float val = (a4[0]*a3 + a4[1]*a2 + a4[2]*a1 + a4[3]*a0) / tot
                              + bias4[l15];
            out[((row0 >> 2) + wv*4 + g)*3 + l15] = val;
        }
    }
}

extern "C" void kernel_launch(void* const* d_in, const int* in_sizes, int n_in,
                              void* d_out, int out_size, void* d_ws, size_t ws_size,
                              hipStream_t stream) {
    const float* feat  = (const float*)d_in[0];
    const float* coord = (const float*)d_in[1];
    const float* cell  = (const float*)d_in[2];
    const float* w0 = (const float*)d_in[3];
    const float* b0 = (const float*)d_in[4];
    const float* w1 = (const float*)d_in[5];
    const float* b1 = (const float*)d_in[6];
    const float* w2 = (const float*)d_in[7];
    const float* b2 = (const float*)d_in[8];
    const float* w3 = (const float*)d_in[9];
    const float* b3 = (const float*)d_in[10];
    const float* w4 = (const float*)d_in[11];
    const float* b4 = (const float*)d_in[12];
    float* out = (float*)d_out;

    f16* featT = (f16*)d_ws;                 // 4*64*64*64 halves = 2 MB
    f16* pw0 = featT + 4*64*64*64;           // 19*16*512 halves (incl. tail+bias)
    f16* pw1 = pw0 + 19*16*512;              // 8*16*512 each (no bias row)
    f16* pw2 = pw1 + 8*16*512;
    f16* pw3 = pw2 + 8*16*512;
    f16* pw4 = pw3 + 8*16*512;               // 8*1*512
    float* P = (float*)(pw4 + 8*512);        // 16384 x 256 f32 = 16 MB

    transpose_feat_k<<<4096, 256, 0, stream>>>(feat, featT);
    pack_w_k2<<<608, 256, 0, stream>>>(w0, b0, pw0, 19, 16, 580, 256, 1);
    pack_w_k2<<<256, 256, 0, stream>>>(w1, b1, pw1,  8, 16, 256, 256, 0);
    pack_w_k2<<<256, 256, 0, stream>>>(w2, b2, pw2,  8, 16, 256, 256, 0);
    pack_w_k2<<<256, 256, 0, stream>>>(w3, b3, pw3,  8, 16, 256, 256, 0);
    pack_w_k2<<< 16, 256, 0, stream>>>(w4, b4, pw4,  8,  1, 256,   3, 0);
    conv0_k<<<256, 256, 0, stream>>>(featT, pw0, P);
    liif_main_k<<<9216, 512, 0, stream>>>(P, pw0, pw1, pw2, pw3, pw4,
                                          b1, b2, b3, b4,
                                          coord, cell, out);
}